// Round 2
// baseline (62.414 us; speedup 1.0000x reference)
//
#include <hip/hip_runtime.h>

#define LENY  1048576
#define NU    (LENY - 1)      // length of u_combined
#define NRBF  11
#define NB    512             // blocks (must be <= guaranteed co-resident capacity)
#define NT    256             // threads per block
#define PERT  8               // consecutive elements per thread
#define CHUNK (NT * PERT)     // 2048 elements per block; NB*CHUNK == LENY

typedef float v4f __attribute__((ext_vector_type(4)));

__device__ __forceinline__ float sigmoid10(float x) {
    x = fminf(10.0f, fmaxf(-10.0f, x));
    return 1.0f / (1.0f + expf(-x));
}

// Fused: compute u_combined (registers + store), block sums, cross-block
// prefix via flag-gated lookback (blocks only wait on EARLIER blocks; grid is
// fully co-resident by construction), then exclusive-scan write of y.
__global__ __launch_bounds__(NT, 4) void rbf_fused(
    const float2* __restrict__ yin,
    const float2* __restrict__ xa,
    const float2* __restrict__ xb,
    const float*  __restrict__ rbfw_raw,
    const float*  __restrict__ weights,
    const float*  __restrict__ g1raw,
    const float*  __restrict__ g2raw,
    float2* __restrict__ yout,
    float2* __restrict__ uout,
    double2* __restrict__ bsums,
    unsigned* __restrict__ flags)
{
    const int b = blockIdx.x, t = threadIdx.x;
    const int base = b * CHUNK + t * PERT;   // first owned element (u-index space)

    // ---- uniform params ----
    const float RBFw   = sigmoid10(rbfw_raw[0]);
    const float wdt    = RBFw * 0.2f;                 // RBFw*(tmax-tmin)/(NRBF-1)
    const float negInv = -1.0f / (2.0f * wdt * wdt);
    const float g1 = expf(g1raw[0]);
    const float g2 = expf(g2raw[0]);
    const float Bf = (float)(1.0 / 60.0);

    float wj[NRBF];
    #pragma unroll
    for (int j = 0; j < NRBF; ++j) wj[j] = weights[j];

    // ---- load 8 consecutive elements per input as 4x float4 (16B/lane) ----
    const v4f* yp = (const v4f*)yin + (base >> 1);
    const v4f* ap = (const v4f*)xa  + (base >> 1);
    const v4f* bp = (const v4f*)xb  + (base >> 1);
    v4f yv[4], av[4], bv[4];
    #pragma unroll
    for (int q = 0; q < 4; ++q) { yv[q] = yp[q]; av[q] = ap[q]; bv[q] = bp[q]; }

    // ---- compute u, keep in registers, accumulate double sums ----
    float ux[PERT], uy[PERT];
    double sx = 0.0, sy = 0.0;
    #pragma unroll
    for (int k = 0; k < PERT; ++k) {
        const int gi = base + k;
        const float ti = ((float)gi - 524287.5f) / 524287.5f;
        float dot = 0.0f;
        #pragma unroll
        for (int j = 0; j < NRBF; ++j) {
            const float c = -1.0f + 0.2f * (float)j;  // linspace(-1,1,11)
            const float d = ti - c;
            dot += expf(d * d * negInv) * wj[j];
        }
        const float wt = sigmoid10(dot);

        const float eyx = yv[k >> 1][(k & 1) * 2 + 0];
        const float eyy = yv[k >> 1][(k & 1) * 2 + 1];
        const float eax = av[k >> 1][(k & 1) * 2 + 0];
        const float eay = av[k >> 1][(k & 1) * 2 + 1];
        const float ebx = bv[k >> 1][(k & 1) * 2 + 0];
        const float eby = bv[k >> 1][(k & 1) * 2 + 1];

        const float u1x = -g1 * (eyx - eax);
        const float u1y = -g1 * (eyy - eay);
        const float u2x = -g2 * (eyx - ebx);
        const float u2y = -g2 * (eyy - eby);
        ux[k] = u1x * (1.0f - wt) + u2x * wt;
        uy[k] = u1y * (1.0f - wt) + u2y * wt;
        sx += (double)(ux[k] * Bf);
        sy += (double)(uy[k] * Bf);
    }

    // ---- store u_combined (last element LENY-1 does not exist in u) ----
    if (base + PERT <= NU) {
        v4f* up = (v4f*)uout + (base >> 1);
        #pragma unroll
        for (int q = 0; q < 4; ++q) {
            v4f r = { ux[2*q], uy[2*q], ux[2*q+1], uy[2*q+1] };
            up[q] = r;
        }
    } else {
        for (int k = 0; k < PERT; ++k)
            if (base + k < NU) uout[base + k] = make_float2(ux[k], uy[k]);
    }

    // ---- block-sum tree reduce ----
    __shared__ double2 sred[NT];
    sred[t] = make_double2(sx, sy);
    __syncthreads();
    #pragma unroll
    for (int s = NT / 2; s > 0; s >>= 1) {
        if (t < s) { sred[t].x += sred[t + s].x; sred[t].y += sred[t + s].y; }
        __syncthreads();
    }
    if (t == 0) {
        bsums[b] = sred[0];   // plain stores, ordered by the release below
        __hip_atomic_store(&flags[b], 1u, __ATOMIC_RELEASE, __HIP_MEMORY_SCOPE_AGENT);
    }

    // ---- wait for all earlier blocks, accumulate block offset ----
    double ox = 0.0, oy = 0.0;
    for (int j = t; j < b; j += NT) {
        unsigned v;
        do {
            v = __hip_atomic_load(&flags[j], __ATOMIC_ACQUIRE, __HIP_MEMORY_SCOPE_AGENT);
            if (!v) __builtin_amdgcn_s_sleep(8);
        } while (!v);
        // values read at coherence point (agent-scope atomics), gated by acquire
        unsigned long long lx = __hip_atomic_load(
            (const unsigned long long*)&bsums[j].x, __ATOMIC_RELAXED, __HIP_MEMORY_SCOPE_AGENT);
        unsigned long long ly = __hip_atomic_load(
            (const unsigned long long*)&bsums[j].y, __ATOMIC_RELAXED, __HIP_MEMORY_SCOPE_AGENT);
        ox += __builtin_bit_cast(double, lx);
        oy += __builtin_bit_cast(double, ly);
    }

    // ---- reduce per-thread offset partials ----
    __syncthreads();          // sred free for reuse (tree reads all complete)
    sred[t] = make_double2(ox, oy);
    __syncthreads();
    #pragma unroll
    for (int s = NT / 2; s > 0; s >>= 1) {
        if (t < s) { sred[t].x += sred[t + s].x; sred[t].y += sred[t + s].y; }
        __syncthreads();
    }
    const double offx = sred[0].x;
    const double offy = sred[0].y;
    __syncthreads();          // everyone has read sred[0] before reuse

    // ---- Hillis-Steele inclusive scan of per-thread sums ----
    sred[t] = make_double2(sx, sy);
    __syncthreads();
    for (int off = 1; off < NT; off <<= 1) {
        double axv = 0.0, ayv = 0.0;
        if (t >= off) { axv = sred[t - off].x; ayv = sred[t - off].y; }
        __syncthreads();
        if (t >= off) { sred[t].x += axv; sred[t].y += ayv; }
        __syncthreads();
    }
    double runx = offx + ((t > 0) ? sred[t - 1].x : 0.0);
    double runy = offy + ((t > 0) ? sred[t - 1].y : 0.0);

    // ---- exclusive-scan write of y (16B-aligned, covers y[0]=yin[0]) ----
    const float2 y0 = yin[0];
    const double y0x = (double)y0.x, y0y = (double)y0.y;

    v4f* wyp = (v4f*)yout + (base >> 1);
    #pragma unroll
    for (int q = 0; q < 4; ++q) {
        const int k0 = 2 * q, k1 = 2 * q + 1;
        const float o0x = (float)(y0x + runx);
        const float o0y = (float)(y0y + runy);
        runx += (double)(ux[k0] * Bf);
        runy += (double)(uy[k0] * Bf);
        const float o1x = (float)(y0x + runx);
        const float o1y = (float)(y0y + runy);
        runx += (double)(ux[k1] * Bf);
        runy += (double)(uy[k1] * Bf);
        v4f r = { o0x, o0y, o1x, o1y };
        wyp[q] = r;
    }
}

extern "C" void kernel_launch(void* const* d_in, const int* in_sizes, int n_in,
                              void* d_out, int out_size, void* d_ws, size_t ws_size,
                              hipStream_t stream) {
    const float2* yin  = (const float2*)d_in[0];
    const float2* xa   = (const float2*)d_in[1];
    const float2* xb   = (const float2*)d_in[2];
    const float*  rbfw = (const float*)d_in[3];
    const float*  wts  = (const float*)d_in[4];
    const float*  g1   = (const float*)d_in[5];
    const float*  g2   = (const float*)d_in[6];

    float*  out  = (float*)d_out;
    float2* yout = (float2*)out;                 // y: LENY x 2
    float2* uout = (float2*)(out + 2 * LENY);    // u_combined: (LENY-1) x 2

    double2*  bsums = (double2*)d_ws;                                  // 8 KB
    unsigned* flags = (unsigned*)((char*)d_ws + NB * sizeof(double2)); // 2 KB

    // flags must be 0 at kernel start every call (d_ws is not re-poisoned
    // between graph replays). Capture-legal: becomes a memset node.
    hipMemsetAsync(flags, 0, NB * sizeof(unsigned), stream);

    rbf_fused<<<NB, NT, 0, stream>>>(yin, xa, xb, rbfw, wts, g1, g2,
                                     yout, uout, bsums, flags);
}

// Round 3
// 29.633 us; speedup vs baseline: 2.1062x; 2.1062x over previous
//
#include <hip/hip_runtime.h>

#define LENY  1048576
#define NU    (LENY - 1)      // length of u_combined
#define NRBF  11
#define NB    512             // blocks; 2/CU needed, 4/CU capacity -> co-resident
#define NT    256             // threads per block
#define PERT  8               // consecutive elements per thread
#define CHUNK (NT * PERT)     // 2048 elements per block; NB*CHUNK == LENY

typedef float v4f __attribute__((ext_vector_type(4)));

__device__ __forceinline__ float sigmoid10(float x) {
    x = fminf(10.0f, fmaxf(-10.0f, x));
    return 1.0f / (1.0f + expf(-x));
}

// Relaxed agent-scope atomics: coherent (reach L3, the cross-XCD coherence
// point) but emit NO buffer_inv / buffer_wbl2 cache maintenance — unlike
// acquire/release, which poisoned round 2 (512 wbl2 + invalidate storm).
__device__ __forceinline__ void st_relaxed_u64(unsigned long long* p, unsigned long long v) {
    __hip_atomic_store(p, v, __ATOMIC_RELAXED, __HIP_MEMORY_SCOPE_AGENT);
}
__device__ __forceinline__ unsigned long long ld_relaxed_u64(const unsigned long long* p) {
    return __hip_atomic_load(p, __ATOMIC_RELAXED, __HIP_MEMORY_SCOPE_AGENT);
}
__device__ __forceinline__ void st_relaxed_u32(unsigned* p, unsigned v) {
    __hip_atomic_store(p, v, __ATOMIC_RELAXED, __HIP_MEMORY_SCOPE_AGENT);
}
__device__ __forceinline__ unsigned ld_relaxed_u32(const unsigned* p) {
    return __hip_atomic_load(p, __ATOMIC_RELAXED, __HIP_MEMORY_SCOPE_AGENT);
}

__global__ __launch_bounds__(NT, 4) void rbf_fused(
    const float2* __restrict__ yin,
    const float2* __restrict__ xa,
    const float2* __restrict__ xb,
    const float*  __restrict__ rbfw_raw,
    const float*  __restrict__ weights,
    const float*  __restrict__ g1raw,
    const float*  __restrict__ g2raw,
    float2* __restrict__ yout,
    float2* __restrict__ uout,
    double2* __restrict__ bsums,
    unsigned* __restrict__ flags)
{
    const int b = blockIdx.x, t = threadIdx.x;
    const int base = b * CHUNK + t * PERT;   // first owned element

    // ---- uniform params ----
    const float RBFw   = sigmoid10(rbfw_raw[0]);
    const float wdt    = RBFw * 0.2f;                 // RBFw*(tmax-tmin)/(NRBF-1)
    const float negInv = -1.0f / (2.0f * wdt * wdt);
    const float g1 = expf(g1raw[0]);
    const float g2 = expf(g2raw[0]);
    const float Bf = (float)(1.0 / 60.0);

    float wj[NRBF];
    #pragma unroll
    for (int j = 0; j < NRBF; ++j) wj[j] = weights[j];

    // ---- 16B/lane loads of 8 consecutive elements per input ----
    const v4f* yp = (const v4f*)yin + (base >> 1);
    const v4f* ap = (const v4f*)xa  + (base >> 1);
    const v4f* bp = (const v4f*)xb  + (base >> 1);
    v4f yv[4], av[4], bv[4];
    #pragma unroll
    for (int q = 0; q < 4; ++q) { yv[q] = yp[q]; av[q] = ap[q]; bv[q] = bp[q]; }

    // ---- compute u in registers, accumulate per-thread double sums ----
    float ux[PERT], uy[PERT];
    double sx = 0.0, sy = 0.0;
    #pragma unroll
    for (int k = 0; k < PERT; ++k) {
        const int gi = base + k;
        const float ti = ((float)gi - 524287.5f) / 524287.5f;
        float dot = 0.0f;
        #pragma unroll
        for (int j = 0; j < NRBF; ++j) {
            const float c = -1.0f + 0.2f * (float)j;  // linspace(-1,1,11)
            const float d = ti - c;
            dot += expf(d * d * negInv) * wj[j];
        }
        const float wt = sigmoid10(dot);

        const float eyx = yv[k >> 1][(k & 1) * 2 + 0];
        const float eyy = yv[k >> 1][(k & 1) * 2 + 1];
        const float eax = av[k >> 1][(k & 1) * 2 + 0];
        const float eay = av[k >> 1][(k & 1) * 2 + 1];
        const float ebx = bv[k >> 1][(k & 1) * 2 + 0];
        const float eby = bv[k >> 1][(k & 1) * 2 + 1];

        const float u1x = -g1 * (eyx - eax);
        const float u1y = -g1 * (eyy - eay);
        const float u2x = -g2 * (eyx - ebx);
        const float u2y = -g2 * (eyy - eby);
        ux[k] = u1x * (1.0f - wt) + u2x * wt;
        uy[k] = u1y * (1.0f - wt) + u2y * wt;
        sx += (double)(ux[k] * Bf);
        sy += (double)(uy[k] * Bf);
    }

    // ---- store u_combined (element NU does not exist) ----
    if (base + PERT <= NU) {
        v4f* up = (v4f*)uout + (base >> 1);
        #pragma unroll
        for (int q = 0; q < 4; ++q) {
            v4f r = { ux[2*q], uy[2*q], ux[2*q+1], uy[2*q+1] };
            up[q] = r;
        }
    } else {
        for (int k = 0; k < PERT; ++k)
            if (base + k < NU) uout[base + k] = make_float2(ux[k], uy[k]);
    }

    // ---- Hillis-Steele inclusive scan of per-thread sums (before lookback:
    //      block total falls out of the scan, and scan is off the wait path) ----
    __shared__ double2 sred[NT];
    sred[t] = make_double2(sx, sy);
    __syncthreads();
    for (int off = 1; off < NT; off <<= 1) {
        double axv = 0.0, ayv = 0.0;
        if (t >= off) { axv = sred[t - off].x; ayv = sred[t - off].y; }
        __syncthreads();
        if (t >= off) { sred[t].x += axv; sred[t].y += ayv; }
        __syncthreads();
    }
    const double myex = (t > 0) ? sred[t - 1].x : 0.0;   // exclusive prefix
    const double myey = (t > 0) ? sred[t - 1].y : 0.0;
    const double2 tot = sred[NT - 1];                    // block total (broadcast)

    // ---- publish: payload (relaxed) -> vmcnt(0) -> flag (relaxed) ----
    if (t == 0) {
        st_relaxed_u64((unsigned long long*)&bsums[b].x, __builtin_bit_cast(unsigned long long, tot.x));
        st_relaxed_u64((unsigned long long*)&bsums[b].y, __builtin_bit_cast(unsigned long long, tot.y));
        asm volatile("s_waitcnt vmcnt(0)" ::: "memory");  // payload at L3 before flag
        st_relaxed_u32(&flags[b], 1u);
    }

    // ---- lookback: relaxed spin (no cache maintenance), then payload ----
    double ox = 0.0, oy = 0.0;
    for (int j = t; j < b; j += NT) {
        unsigned v;
        do {
            v = ld_relaxed_u32(&flags[j]);
            if (!v) __builtin_amdgcn_s_sleep(4);
        } while (!v);
        asm volatile("" ::: "memory");   // don't hoist payload loads above spin
        ox += __builtin_bit_cast(double, ld_relaxed_u64((const unsigned long long*)&bsums[j].x));
        oy += __builtin_bit_cast(double, ld_relaxed_u64((const unsigned long long*)&bsums[j].y));
    }

    // ---- reduce offset partials: wave shfl, then 4 wave totals via LDS ----
    #pragma unroll
    for (int d = 32; d > 0; d >>= 1) {
        ox += __shfl_down(ox, d);
        oy += __shfl_down(oy, d);
    }
    __shared__ double2 wred[NT / 64];
    const int wid = t >> 6, lane = t & 63;
    if (lane == 0) wred[wid] = make_double2(ox, oy);
    __syncthreads();
    const double offx = wred[0].x + wred[1].x + wred[2].x + wred[3].x;
    const double offy = wred[0].y + wred[1].y + wred[2].y + wred[3].y;

    // ---- exclusive-scan write of y (16B stores; covers y[0]=yin[0]) ----
    double runx = offx + myex;
    double runy = offy + myey;
    const float2 y0 = yin[0];
    const double y0x = (double)y0.x, y0y = (double)y0.y;

    v4f* wyp = (v4f*)yout + (base >> 1);
    #pragma unroll
    for (int q = 0; q < 4; ++q) {
        const int k0 = 2 * q, k1 = 2 * q + 1;
        const float o0x = (float)(y0x + runx);
        const float o0y = (float)(y0y + runy);
        runx += (double)(ux[k0] * Bf);
        runy += (double)(uy[k0] * Bf);
        const float o1x = (float)(y0x + runx);
        const float o1y = (float)(y0y + runy);
        runx += (double)(ux[k1] * Bf);
        runy += (double)(uy[k1] * Bf);
        v4f r = { o0x, o0y, o1x, o1y };
        wyp[q] = r;
    }
}

extern "C" void kernel_launch(void* const* d_in, const int* in_sizes, int n_in,
                              void* d_out, int out_size, void* d_ws, size_t ws_size,
                              hipStream_t stream) {
    const float2* yin  = (const float2*)d_in[0];
    const float2* xa   = (const float2*)d_in[1];
    const float2* xb   = (const float2*)d_in[2];
    const float*  rbfw = (const float*)d_in[3];
    const float*  wts  = (const float*)d_in[4];
    const float*  g1   = (const float*)d_in[5];
    const float*  g2   = (const float*)d_in[6];

    float*  out  = (float*)d_out;
    float2* yout = (float2*)out;                 // y: LENY x 2
    float2* uout = (float2*)(out + 2 * LENY);    // u_combined: (LENY-1) x 2

    double2*  bsums = (double2*)d_ws;                                  // 8 KB
    unsigned* flags = (unsigned*)((char*)d_ws + NB * sizeof(double2)); // 2 KB

    // flags must be 0 at kernel start every call (graph replays don't
    // re-poison d_ws). Capture-legal: becomes a memset node.
    hipMemsetAsync(flags, 0, NB * sizeof(unsigned), stream);

    rbf_fused<<<NB, NT, 0, stream>>>(yin, xa, xb, rbfw, wts, g1, g2,
                                     yout, uout, bsums, flags);
}

// Round 4
// 24.413 us; speedup vs baseline: 2.5566x; 1.2138x over previous
//
#include <hip/hip_runtime.h>

#define LENY  1048576
#define NU    (LENY - 1)      // length of u_combined
#define NRBF  11
#define NB    1024            // blocks; 4/CU needed, ~8/CU capacity -> co-resident
#define NT    256             // threads per block
#define PERT  4               // consecutive elements per thread
#define CHUNK (NT * PERT)     // 1024 elements per block; NB*CHUNK == LENY

typedef float v4f __attribute__((ext_vector_type(4)));

#define L2E 1.44269504088896340736f   // log2(e)

// fast exp(x) via v_exp_f32 (2^x); ~1 ulp, plenty for this tolerance
__device__ __forceinline__ float fexp(float x) {
    return __builtin_amdgcn_exp2f(x * L2E);
}
__device__ __forceinline__ float sigmoid10(float x) {
    x = fminf(10.0f, fmaxf(-10.0f, x));
    // 1/(1+exp(-x)) with native exp2 + rcp
    const float e = __builtin_amdgcn_exp2f(-x * L2E);
    return __builtin_amdgcn_rcpf(1.0f + e);
}

// Relaxed agent-scope atomics: reach the coherence point (L3) with NO
// buffer_inv/buffer_wbl2 maintenance (acq/rel poisoned round 2: 62us).
__device__ __forceinline__ void st_relaxed_u64(unsigned long long* p, unsigned long long v) {
    __hip_atomic_store(p, v, __ATOMIC_RELAXED, __HIP_MEMORY_SCOPE_AGENT);
}
__device__ __forceinline__ unsigned long long ld_relaxed_u64(const unsigned long long* p) {
    return __hip_atomic_load(p, __ATOMIC_RELAXED, __HIP_MEMORY_SCOPE_AGENT);
}
__device__ __forceinline__ void st_relaxed_u32(unsigned* p, unsigned v) {
    __hip_atomic_store(p, v, __ATOMIC_RELAXED, __HIP_MEMORY_SCOPE_AGENT);
}
__device__ __forceinline__ unsigned ld_relaxed_u32(const unsigned* p) {
    return __hip_atomic_load(p, __ATOMIC_RELAXED, __HIP_MEMORY_SCOPE_AGENT);
}

__global__ __launch_bounds__(NT, 4) void rbf_fused(
    const float2* __restrict__ yin,
    const float2* __restrict__ xa,
    const float2* __restrict__ xb,
    const float*  __restrict__ rbfw_raw,
    const float*  __restrict__ weights,
    const float*  __restrict__ g1raw,
    const float*  __restrict__ g2raw,
    float2* __restrict__ yout,
    float2* __restrict__ uout,
    double2* __restrict__ bsums,
    unsigned* __restrict__ flags)
{
    const int b = blockIdx.x, t = threadIdx.x;
    const int lane = t & 63, wid = t >> 6;
    const int base = b * CHUNK + t * PERT;   // first owned element

    // ---- uniform params ----
    const float RBFw    = sigmoid10(rbfw_raw[0]);
    const float wdt     = RBFw * 0.2f;               // RBFw*(tmax-tmin)/(NRBF-1)
    const float negInvL = -L2E / (2.0f * wdt * wdt); // folds log2e into the RBF exp
    const float g1 = fexp(g1raw[0]);
    const float g2 = fexp(g2raw[0]);
    const float Bf = (float)(1.0 / 60.0);
    const float2 y0 = yin[0];

    float wj[NRBF];
    #pragma unroll
    for (int j = 0; j < NRBF; ++j) wj[j] = weights[j];

    // ---- 16B loads: 4 consecutive elements per input = 2x float4 each ----
    const v4f* yp = (const v4f*)yin + (base >> 1);
    const v4f* ap = (const v4f*)xa  + (base >> 1);
    const v4f* bp = (const v4f*)xb  + (base >> 1);
    v4f yv[2], av[2], bv[2];
    #pragma unroll
    for (int q = 0; q < 2; ++q) { yv[q] = yp[q]; av[q] = ap[q]; bv[q] = bp[q]; }

    // ---- compute u in registers, per-thread double sums ----
    float ux[PERT], uy[PERT];
    double sx = 0.0, sy = 0.0;
    #pragma unroll
    for (int k = 0; k < PERT; ++k) {
        const int gi = base + k;
        const float ti = ((float)gi - 524287.5f) / 524287.5f;
        float dot = 0.0f;
        #pragma unroll
        for (int j = 0; j < NRBF; ++j) {
            const float c = -1.0f + 0.2f * (float)j;  // linspace(-1,1,11)
            const float d = ti - c;
            dot += __builtin_amdgcn_exp2f(d * d * negInvL) * wj[j];
        }
        const float wt = sigmoid10(dot);

        const float eyx = yv[k >> 1][(k & 1) * 2 + 0];
        const float eyy = yv[k >> 1][(k & 1) * 2 + 1];
        const float eax = av[k >> 1][(k & 1) * 2 + 0];
        const float eay = av[k >> 1][(k & 1) * 2 + 1];
        const float ebx = bv[k >> 1][(k & 1) * 2 + 0];
        const float eby = bv[k >> 1][(k & 1) * 2 + 1];

        const float u1x = -g1 * (eyx - eax);
        const float u1y = -g1 * (eyy - eay);
        const float u2x = -g2 * (eyx - ebx);
        const float u2y = -g2 * (eyy - eby);
        ux[k] = u1x * (1.0f - wt) + u2x * wt;
        uy[k] = u1y * (1.0f - wt) + u2y * wt;
        sx += (double)(ux[k] * Bf);     // phantom last element harmless: its block
        sy += (double)(uy[k] * Bf);     // total is never consumed, prefix unaffected
    }

    // ---- block scan: wave shfl_up scan + 1 barrier (was 16-barrier H-S) ----
    double ix = sx, iy = sy;
    #pragma unroll
    for (int d = 1; d < 64; d <<= 1) {
        const double px = __shfl_up(ix, d, 64);
        const double py = __shfl_up(iy, d, 64);
        if (lane >= d) { ix += px; iy += py; }
    }
    __shared__ double2 wtot[NT / 64];
    if (lane == 63) wtot[wid] = make_double2(ix, iy);
    __syncthreads();
    double wbx = 0.0, wby = 0.0;
    #pragma unroll
    for (int w = 0; w < NT / 64; ++w)
        if (w < wid) { wbx += wtot[w].x; wby += wtot[w].y; }
    const double totx = wtot[0].x + wtot[1].x + wtot[2].x + wtot[3].x;
    const double toty = wtot[0].y + wtot[1].y + wtot[2].y + wtot[3].y;
    const double pex = __shfl_up(ix, 1, 64);
    const double pey = __shfl_up(iy, 1, 64);
    const double myex = (lane == 0) ? wbx : wbx + pex;  // exclusive in-block prefix
    const double myey = (lane == 0) ? wby : wby + pey;

    // ---- publish ASAP: payload -> vmcnt(0) -> flag (all relaxed) ----
    if (t == 0) {
        st_relaxed_u64((unsigned long long*)&bsums[b].x, __builtin_bit_cast(unsigned long long, totx));
        st_relaxed_u64((unsigned long long*)&bsums[b].y, __builtin_bit_cast(unsigned long long, toty));
        asm volatile("s_waitcnt vmcnt(0)" ::: "memory");  // payload at L3 before flag
        st_relaxed_u32(&flags[b], 1u);
    }

    // ---- store u AFTER publish (overlaps the wait) ----
    if (base + PERT <= NU) {
        v4f* up = (v4f*)uout + (base >> 1);
        #pragma unroll
        for (int q = 0; q < 2; ++q) {
            v4f r = { ux[2*q], uy[2*q], ux[2*q+1], uy[2*q+1] };
            up[q] = r;
        }
    } else {
        for (int k = 0; k < PERT; ++k)
            if (base + k < NU) uout[base + k] = make_float2(ux[k], uy[k]);
    }

    // ---- lookback: relaxed spin on earlier blocks' flags ----
    double ox = 0.0, oy = 0.0;
    for (int j = t; j < b; j += NT) {
        while (ld_relaxed_u32(&flags[j]) == 0u) __builtin_amdgcn_s_sleep(2);
        asm volatile("" ::: "memory");   // don't hoist payload loads above spin
        ox += __builtin_bit_cast(double, ld_relaxed_u64((const unsigned long long*)&bsums[j].x));
        oy += __builtin_bit_cast(double, ld_relaxed_u64((const unsigned long long*)&bsums[j].y));
    }

    // ---- reduce offset partials: wave shfl, then 4 wave totals via LDS ----
    #pragma unroll
    for (int d = 32; d > 0; d >>= 1) {
        ox += __shfl_down(ox, d);
        oy += __shfl_down(oy, d);
    }
    __shared__ double2 wred[NT / 64];
    if (lane == 0) wred[wid] = make_double2(ox, oy);
    __syncthreads();
    const double offx = wred[0].x + wred[1].x + wred[2].x + wred[3].x;
    const double offy = wred[0].y + wred[1].y + wred[2].y + wred[3].y;

    // ---- exclusive-scan write of y (16B stores; y[0]=yin[0] falls out) ----
    double runx = offx + myex;
    double runy = offy + myey;
    const double y0x = (double)y0.x, y0y = (double)y0.y;

    v4f* wyp = (v4f*)yout + (base >> 1);
    #pragma unroll
    for (int q = 0; q < 2; ++q) {
        const int k0 = 2 * q, k1 = 2 * q + 1;
        const float o0x = (float)(y0x + runx);
        const float o0y = (float)(y0y + runy);
        runx += (double)(ux[k0] * Bf);
        runy += (double)(uy[k0] * Bf);
        const float o1x = (float)(y0x + runx);
        const float o1y = (float)(y0y + runy);
        runx += (double)(ux[k1] * Bf);
        runy += (double)(uy[k1] * Bf);
        v4f r = { o0x, o0y, o1x, o1y };
        wyp[q] = r;
    }
}

extern "C" void kernel_launch(void* const* d_in, const int* in_sizes, int n_in,
                              void* d_out, int out_size, void* d_ws, size_t ws_size,
                              hipStream_t stream) {
    const float2* yin  = (const float2*)d_in[0];
    const float2* xa   = (const float2*)d_in[1];
    const float2* xb   = (const float2*)d_in[2];
    const float*  rbfw = (const float*)d_in[3];
    const float*  wts  = (const float*)d_in[4];
    const float*  g1   = (const float*)d_in[5];
    const float*  g2   = (const float*)d_in[6];

    float*  out  = (float*)d_out;
    float2* yout = (float2*)out;                 // y: LENY x 2
    float2* uout = (float2*)(out + 2 * LENY);    // u_combined: (LENY-1) x 2

    double2*  bsums = (double2*)d_ws;                                  // 16 KB
    unsigned* flags = (unsigned*)((char*)d_ws + NB * sizeof(double2)); //  4 KB

    // flags must be 0 at kernel start on every call (graph replays don't
    // re-poison d_ws). Capture-legal: becomes a memset node.
    hipMemsetAsync(flags, 0, NB * sizeof(unsigned), stream);

    rbf_fused<<<NB, NT, 0, stream>>>(yin, xa, xb, rbfw, wts, g1, g2,
                                     yout, uout, bsums, flags);
}